// Round 7
// baseline (657.252 us; speedup 1.0000x reference)
//
#include <hip/hip_runtime.h>
#include <hip/hip_bf16.h>

// MHAGCN: x(4096,6,1024) f32 -> out(4096,6,256) f32. Internal bf16 + MFMA.
// R13: eliminate Q/KV panels algebraically. softmax(QKV^T) row-constant
// terms cancel exactly; S ~ X (W1 W2^T) X^T + v[d], v = X (W2 a1).
//  - MhT_h = W2_h W1_h^T precomputed (one (4,4,5) gemm256 dispatch, 10 MB).
//  - gemmS: Y = X @ M_h tiled (96,4,5); Y NEVER hits HBM: epilogue stages
//    the 256x256 Y-tile in LDS (XOR-swizzled) and runs the verified
//    16-row-packed scores MFMA vs X (global, L3-hot), writing per-n-tile
//    partials S4[4][4096][5][36] f32 (no atomics; each entry written once).
//  - mid_ax: sum 4 partials + v, softmax -> A -> Xa in place. No panel reads.
//  - v computed via w2a1 (= 0 on these inputs: ab1=0; exact no-op safety).
// R11/R12 lesson: every variant of "re-read 250MB panels" costs 630-650us;
// the round-trip itself was the sink. Also: vmcnt(0)+barrier added before
// epilogue LDS reuse in both 256^2 kernels (latent global_load_lds race).

using bf16 = __hip_bfloat16;
using s16x8 = __attribute__((ext_vector_type(8))) short;
using f32x4 = __attribute__((ext_vector_type(4))) float;

#define AS1(p) ((__attribute__((address_space(1))) void*)((void*)(p)))
#define AS3(p) ((__attribute__((address_space(3))) void*)(p))

#if defined(__has_builtin)
#if __has_builtin(__builtin_amdgcn_global_load_lds)
#define HAVE_GLL 1
#endif
#endif

__device__ __forceinline__ float s2f(short s) {
  union { unsigned int u; float f; } c;
  c.u = ((unsigned int)(unsigned short)s) << 16;
  return c.f;
}
__device__ __forceinline__ short f2s(float x) {
  bf16 b = __float2bfloat16(x);
  short s;
  __builtin_memcpy(&s, &b, 2);
  return s;
}

// GEMM output-routing job (selected per blockIdx.z)
struct GJob {
  const bf16* Bt;
  const float* bias;
  int boff;
  bf16* out;
  const bf16* Aj;  // per-job A override (nullptr -> use kernel arg A)
};
struct GJobs10 {
  GJob j[10];
};

// ---------------------------------------------------------------------------
// prep: x cvt [0,12288) | aW1 cvt [12288,13568) | aW2 cvt [13568,14848)
//       gW1 T [14848,15360) | gW2 T [15360,15488) | w2a1 [15488,15508)
// ---------------------------------------------------------------------------
__global__ __launch_bounds__(256) void prep_kernel(
    const float* __restrict__ x, bf16* __restrict__ Xb,
    const float* __restrict__ aW1, bf16* __restrict__ W1b,
    const float* __restrict__ aW2, bf16* __restrict__ W2b,
    const float* __restrict__ gW1, bf16* __restrict__ G1T,
    const float* __restrict__ gW2, bf16* __restrict__ G2T,
    const float* __restrict__ ab1, float* __restrict__ w2a1) {
  const int bid = blockIdx.x, tid = threadIdx.x;
  __shared__ short tile[32][33];

  if (bid < 12288) {  // x -> Xb (bf16), 8 els/thread
    int i = bid * 256 + tid;  // < 3145728
    float4 p0 = ((const float4*)x)[i * 2];
    float4 p1 = ((const float4*)x)[i * 2 + 1];
    s16x8 v;
    v[0] = f2s(p0.x); v[1] = f2s(p0.y); v[2] = f2s(p0.z); v[3] = f2s(p0.w);
    v[4] = f2s(p1.x); v[5] = f2s(p1.y); v[6] = f2s(p1.z); v[7] = f2s(p1.w);
    ((s16x8*)Xb)[i] = v;
    return;
  }
  if (bid < 14848) {  // aW1 / aW2 straight cvt (5x1024x512 each)
    const float* src = (bid < 13568) ? aW1 : aW2;
    bf16* dst = (bid < 13568) ? W1b : W2b;
    int i = ((bid < 13568) ? (bid - 12288) : (bid - 13568)) * 256 + tid;  // < 327680
    float4 p0 = ((const float4*)src)[i * 2];
    float4 p1 = ((const float4*)src)[i * 2 + 1];
    s16x8 v;
    v[0] = f2s(p0.x); v[1] = f2s(p0.y); v[2] = f2s(p0.z); v[3] = f2s(p0.w);
    v[4] = f2s(p1.x); v[5] = f2s(p1.y); v[6] = f2s(p1.z); v[7] = f2s(p1.w);
    ((s16x8*)dst)[i] = v;
    return;
  }
  if (bid < 15488) {  // transposes (gW1: 512 blocks, gW2: 128 blocks)
    const float* src; short* dst; int R, C, bx, by;
    if (bid < 15360) {
      int r = bid - 14848;
      src = gW1; dst = (short*)G1T; R = 1024; C = 512; bx = r & 31; by = r >> 5;
    } else {
      int r = bid - 15360;
      src = gW2; dst = (short*)G2T; R = 512; C = 256; bx = r & 15; by = r >> 4;
    }
    const int tx = tid & 31, ty = tid >> 5;  // (32, 8)
    const int r0 = bx * 32, c0 = by * 32;
#pragma unroll
    for (int i = 0; i < 4; ++i)
      tile[ty + i * 8][tx] = f2s(src[(size_t)(r0 + ty + i * 8) * C + c0 + tx]);
    __syncthreads();
#pragma unroll
    for (int i = 0; i < 4; ++i)
      dst[(size_t)(c0 + ty + i * 8) * R + r0 + tx] = tile[tx][ty + i * 8];
    return;
  }
  // w2a1[h][l] = sum_mid aW2[h][l][mid] * ab1[h][mid]  (5120 dots of 512)
  int idx = (bid - 15488) * 256 + tid;
  if (idx < 5120) {
    int h = idx >> 10, l = idx & 1023;
    const float* wp = aW2 + (size_t)h * 524288 + (size_t)l * 512;
    const float* bp = ab1 + h * 512;
    float s = 0.f;
    for (int m = 0; m < 512; ++m) s += wp[m] * bp[m];
    w2a1[h * 1024 + l] = s;
  }
}

// ---------------------------------------------------------------------------
// Legacy 128x128 GEMM (m97 structure) — used for the HW gemm (N=256:
// (192,2)=384 light blocks beat 96 blocks of 256^2).
// ---------------------------------------------------------------------------
template <int AF32>
__global__ __launch_bounds__(256) void gemm_bt(
    const void* __restrict__ Ag,
    const bf16* __restrict__ Bt0, const bf16* __restrict__ Bt1,
    const float* __restrict__ bias0, const float* __restrict__ bias1, int boff,
    bf16* __restrict__ out0, bf16* __restrict__ out1,
    int M, int N, int K) {
  const bf16* Bt = (blockIdx.z == 0) ? Bt0 : Bt1;
  const float* bias = (blockIdx.z == 0) ? bias0 : bias1;
  bf16* Cg = (blockIdx.z == 0) ? out0 : out1;

  __shared__ short lA[128 * 32];
  __shared__ short lB[128 * 32];

  const int tid = threadIdx.x;
  const int lane = tid & 63, w = tid >> 6;
  const int wr = w >> 1, wc = w & 1;
  const int l16 = lane & 15, quad = lane >> 4;
  const int lrow = lane >> 2;
  const int scol = (((lane & 3) ^ ((lane >> 3) & 3)) * 8);

  const size_t rm0 = (size_t)blockIdx.x * 128;
  const size_t cn0 = (size_t)blockIdx.y * 128;

  f32x4 acc[4][4];
#pragma unroll
  for (int i = 0; i < 4; ++i)
#pragma unroll
    for (int j = 0; j < 4; ++j) acc[i][j] = (f32x4){0.f, 0.f, 0.f, 0.f};

  for (int kb = 0; kb < K; kb += 32) {
#pragma unroll
    for (int t = 0; t < 2; ++t) {
      int chunk = w * 2 + t;
      int row = chunk * 16 + lrow;
      const bf16* gb = Bt + (cn0 + row) * (size_t)K + kb + scol;
#ifdef HAVE_GLL
      __builtin_amdgcn_global_load_lds(AS1(gb), AS3(lB + chunk * 512), 16, 0, 0);
#else
      *(s16x8*)(lB + chunk * 512 + lane * 8) = *(const s16x8*)gb;
#endif
      if (AF32) {
        const float* ga = (const float*)Ag + (rm0 + row) * (size_t)K + kb + scol;
        float4 p0 = *(const float4*)ga;
        float4 p1 = *(const float4*)(ga + 4);
        s16x8 v;
        v[0] = f2s(p0.x); v[1] = f2s(p0.y); v[2] = f2s(p0.z); v[3] = f2s(p0.w);
        v[4] = f2s(p1.x); v[5] = f2s(p1.y); v[6] = f2s(p1.z); v[7] = f2s(p1.w);
        *(s16x8*)(lA + chunk * 512 + lane * 8) = v;
      } else {
        const bf16* ga = (const bf16*)Ag + (rm0 + row) * (size_t)K + kb + scol;
#ifdef HAVE_GLL
        __builtin_amdgcn_global_load_lds(AS1(ga), AS3(lA + chunk * 512), 16, 0, 0);
#else
        *(s16x8*)(lA + chunk * 512 + lane * 8) = *(const s16x8*)ga;
#endif
      }
    }
    __syncthreads();

    const int q2 = (quad ^ ((l16 >> 1) & 3)) * 8;
    s16x8 af[4], bfv[4];
#pragma unroll
    for (int i = 0; i < 4; ++i) {
      af[i] = *(const s16x8*)(lA + (wr * 64 + i * 16 + l16) * 32 + q2);
      bfv[i] = *(const s16x8*)(lB + (wc * 64 + i * 16 + l16) * 32 + q2);
    }
#pragma unroll
    for (int i = 0; i < 4; ++i)
#pragma unroll
      for (int j = 0; j < 4; ++j)
        acc[i][j] = __builtin_amdgcn_mfma_f32_16x16x32_bf16(af[i], bfv[j], acc[i][j], 0, 0, 0);
    __syncthreads();
  }

#pragma unroll
  for (int j = 0; j < 4; ++j) {
    size_t col = cn0 + wc * 64 + j * 16 + l16;
    float bv = bias ? bias[boff + col] : 0.f;
#pragma unroll
    for (int i = 0; i < 4; ++i) {
      size_t rowb = rm0 + wr * 64 + i * 16 + quad * 4;
#pragma unroll
      for (int r = 0; r < 4; ++r) {
        float v = acc[i][j][r] + bv;
        Cg[(rowb + r) * (size_t)N + col] = __float2bfloat16(v);
      }
    }
  }
}

// ---------------------------------------------------------------------------
// 256x256 8-phase GEMM (m201 template). Inner loop identical to R7-R12
// (verified). Per-z GJob (with optional per-job A), optional fused
// bias+PReLU+BN1 epilogue (epi_z), LDS-staged coalesced output stores.
// vmcnt(0)+barrier before epilogue LDS reuse (pending global_load_lds race).
// ---------------------------------------------------------------------------
__global__ __launch_bounds__(512, 2) void gemm256_8ph(
    const bf16* __restrict__ A, GJobs10 jobs, int epi_z,
    const float* __restrict__ prelu_p,
    const float* __restrict__ bn_g, const float* __restrict__ bn_b,
    const float* __restrict__ bn_m, const float* __restrict__ bn_v,
    int M, int N, int K) {
  const GJob jb = jobs.j[blockIdx.z];
  const bf16* Ae = jb.Aj ? jb.Aj : A;
  const bf16* Bt = jb.Bt;
  const float* bias = jb.bias;
  const int boff = jb.boff;
  bf16* Cg = jb.out;
  const bool EPI = (epi_z == (int)blockIdx.z);

  __shared__ __attribute__((aligned(16))) short ldsS[65536];  // 128 KiB
  __shared__ float epi_s[12];

  const int tid = threadIdx.x;
  const int w = tid >> 6, l = tid & 63;
  const int l16 = l & 15, quad = l >> 4;
  const int wr = w >> 2, wc = w & 3;

  if (EPI && tid < 6) {
    float s = bn_g[tid] * rsqrtf(bn_v[tid] + 1e-5f);
    epi_s[tid] = s;
    epi_s[6 + tid] = bn_b[tid] - bn_m[tid] * s;
  }

  const size_t rm0 = (size_t)blockIdx.x * 256;
  const size_t cn0 = (size_t)blockIdx.y * 256;

  const int colS = ((l & 7) ^ (l >> 3)) * 8;       // shorts
  const int rowS = w * 16 + (l >> 3);              // + g*8 + h*128
  const short* pAs = (const short*)Ae + (rm0 + rowS) * (size_t)K + colS;
  const short* pBs = (const short*)Bt + (cn0 + rowS) * (size_t)K + colS;

  const int u0 = (quad ^ (l16 & 7)) * 8;
  const int u1 = ((quad + 4) ^ (l16 & 7)) * 8;

  f32x4 acc[8][4];
#pragma unroll
  for (int i = 0; i < 8; ++i)
#pragma unroll
    for (int j2i = 0; j2i < 4; ++j2i) acc[i][j2i] = (f32x4){0.f, 0.f, 0.f, 0.f};

  s16x8 af[4][2], bf0[2][2], bf1[2][2];

  const int T = K >> 6;  // K-tiles of 64

#ifdef HAVE_GLL
#define SA(BUF, H, KB) do {                                                          \
    __builtin_amdgcn_global_load_lds(AS1(pAs + (size_t)((H) * 128) * K + (KB)),      \
        AS3(ldsS + (BUF) * 32768 + (H) * 8192 + w * 1024), 16, 0, 0);                \
    __builtin_amdgcn_global_load_lds(AS1(pAs + (size_t)((H) * 128 + 8) * K + (KB)),  \
        AS3(ldsS + (BUF) * 32768 + (H) * 8192 + w * 1024 + 512), 16, 0, 0);          \
  } while (0)
#define SB(BUF, H, KB) do {                                                          \
    __builtin_amdgcn_global_load_lds(AS1(pBs + (size_t)((H) * 128) * K + (KB)),      \
        AS3(ldsS + (BUF) * 32768 + 16384 + (H) * 8192 + w * 1024), 16, 0, 0);        \
    __builtin_amdgcn_global_load_lds(AS1(pBs + (size_t)((H) * 128 + 8) * K + (KB)),  \
        AS3(ldsS + (BUF) * 32768 + 16384 + (H) * 8192 + w * 1024 + 512), 16, 0, 0);  \
  } while (0)
#else
#define SA(BUF, H, KB) do {                                                          \
    *(s16x8*)(ldsS + (BUF) * 32768 + (H) * 8192 + w * 1024 + l * 8) =                \
        *(const s16x8*)(pAs + (size_t)((H) * 128) * K + (KB));                       \
    *(s16x8*)(ldsS + (BUF) * 32768 + (H) * 8192 + w * 1024 + 512 + l * 8) =          \
        *(const s16x8*)(pAs + (size_t)((H) * 128 + 8) * K + (KB));                   \
  } while (0)
#define SB(BUF, H, KB) do {                                                          \
    *(s16x8*)(ldsS + (BUF) * 32768 + 16384 + (H) * 8192 + w * 1024 + l * 8) =        \
        *(const s16x8*)(pBs + (size_t)((H) * 128) * K + (KB));                       \
    *(s16x8*)(ldsS + (BUF) * 32768 + 16384 + (H) * 8192 + w * 1024 + 512 + l * 8) =  \
        *(const s16x8*)(pBs + (size_t)((H) * 128 + 8) * K + (KB));                   \
  } while (0)
#endif

#define LDA(BUF, MH) do {                                                            \
    _Pragma("unroll") for (int i = 0; i < 4; ++i) {                                  \
      const short* bse = ldsS + (BUF) * 32768 + wr * 8192 + (MH) * 4096 +            \
                         i * 1024 + l16 * 64;                                        \
      af[i][0] = *(const s16x8*)(bse + u0);                                          \
      af[i][1] = *(const s16x8*)(bse + u1);                                          \
    }                                                                                \
  } while (0)

#define LDB(BUF, NH, DST) do {                                                       \
    _Pragma("unroll") for (int n = 0; n < 2; ++n) {                                  \
      const short* bse = ldsS + (BUF) * 32768 + 16384 + (wc >> 1) * 8192 +           \
                         (wc & 1) * 4096 + (NH) * 2048 + n * 1024 + l16 * 64;        \
      DST[n][0] = *(const s16x8*)(bse + u0);                                         \
      DST[n][1] = *(const s16x8*)(bse + u1);                                         \
    }                                                                                \
  } while (0)

#define MFMAQ(MH, NH, BSET) do {                                                     \
    _Pragma("unroll") for (int i = 0; i < 4; ++i)                                    \
      _Pragma("unroll") for (int n = 0; n < 2; ++n) {                                \
        acc[(MH) * 4 + i][(NH) * 2 + n] = __builtin_amdgcn_mfma_f32_16x16x32_bf16(   \
            af[i][0], BSET[n][0], acc[(MH) * 4 + i][(NH) * 2 + n], 0, 0, 0);         \
        acc[(MH) * 4 + i][(NH) * 2 + n] = __builtin_amdgcn_mfma_f32_16x16x32_bf16(   \
            af[i][1], BSET[n][1], acc[(MH) * 4 + i][(NH) * 2 + n], 0, 0, 0);         \
      }                                                                              \
  } while (0)

#define BARX() asm volatile("s_barrier" ::: "memory")
#define LGKM0() do { asm volatile("s_waitcnt lgkmcnt(0)" ::: "memory");              \
                     __builtin_amdgcn_sched_barrier(0); } while (0)
#define VM6() do { asm volatile("s_waitcnt vmcnt(6)" ::: "memory");                  \
                   __builtin_amdgcn_sched_barrier(0); } while (0)
#define VM0() do { asm volatile("s_waitcnt vmcnt(0)" ::: "memory");                  \
                   __builtin_amdgcn_sched_barrier(0); } while (0)

#define TILE_STEP(BUF, t) do {                                                       \
    const int kN_ = ((t) + 1 < T ? (t) + 1 : T - 1) << 6;                            \
    const int k2_ = ((t) + 2 < T ? (t) + 2 : T - 1) << 6;                            \
    LDA(BUF, 0); LDB(BUF, 0, bf0); LDB(BUF, 1, bf1);                                 \
    SA((BUF) ^ 1, 1, kN_);                                                           \
    BARX(); LGKM0();                                                                 \
    __builtin_amdgcn_s_setprio(1); MFMAQ(0, 0, bf0); __builtin_amdgcn_s_setprio(0);  \
    BARX();                                                                          \
    SB(BUF, 0, k2_);                                                                 \
    BARX();                                                                          \
    __builtin_amdgcn_s_setprio(1); MFMAQ(0, 1, bf1); __builtin_amdgcn_s_setprio(0);  \
    BARX();                                                                          \
    LDA(BUF, 1);                                                                     \
    SB(BUF, 1, k2_);                                                                 \
    BARX(); LGKM0();                                                                 \
    __builtin_amdgcn_s_setprio(1); MFMAQ(1, 1, bf1); __builtin_amdgcn_s_setprio(0);  \
    BARX();                                                                          \
    SA(BUF, 0, k2_);                                                                 \
    VM6();                                                                           \
    BARX();                                                                          \
    __builtin_amdgcn_s_setprio(1); MFMAQ(1, 0, bf0); __builtin_amdgcn_s_setprio(0);  \
    BARX();                                                                          \
  } while (0)

  {
    const int k1_ = (T > 1 ? 1 : 0) << 6;
    SB(0, 0, 0); SB(0, 1, 0); SA(0, 0, 0); SA(0, 1, 0);
    SB(1, 0, k1_); SB(1, 1, k1_); SA(1, 0, k1_);
    VM6();
    BARX();
  }

  for (int t = 0; t < T; t += 2) {
    TILE_STEP(0, t);
    TILE_STEP(1, t + 1);
  }

  // ---- epilogue: drain pending glls, stage wave tile in private LDS, then
  // coalesced 16B/lane stores. D row = quad*4+r, col = l16 (m89-verified).
  VM0();
  BARX();
  float pa = EPI ? prelu_p[0] : 0.f;
  short* st = ldsS + w * 8192;
#pragma unroll
  for (int jj = 0; jj < 4; ++jj) {
    int coll = jj * 16 + l16;
    float bv = bias ? bias[boff + (int)cn0 + wc * 64 + coll] : 0.f;
#pragma unroll
    for (int i = 0; i < 8; ++i) {
#pragma unroll
      for (int r = 0; r < 4; ++r) {
        int rowl = i * 16 + quad * 4 + r;
        float v = acc[i][jj][r] + bv;
        if (EPI) {
          v = (v >= 0.f) ? v : pa * v;
          int c = (int)((rm0 + wr * 128 + rowl) % 6);
          v = v * epi_s[c] + epi_s[6 + c];
        }
        st[rowl * 64 + coll] = f2s(v);
      }
    }
  }
  __syncthreads();
#pragma unroll
  for (int it = 0; it < 16; ++it) {
    int rowl = it * 8 + (l >> 3);
    int cch = (l & 7) * 8;
    s16x8 vv = *(const s16x8*)(st + rowl * 64 + cch);
    *(s16x8*)((short*)Cg + (rm0 + wr * 128 + rowl) * (size_t)N +
              cn0 + wc * 64 + cch) = vv;
  }
#undef SA
#undef SB
#undef LDA
#undef LDB
#undef MFMAQ
#undef BARX
#undef LGKM0
#undef VM6
#undef VM0
#undef TILE_STEP
}

// ---------------------------------------------------------------------------
// gemmS: Y = X @ M_h (256x256 tiles, same verified 8-phase loop), with a
// fused scores epilogue. grid (96, 4, 5): x=row-tile, y=m-tile (N=1024),
// z=head. Y tile staged to XOR-swizzled LDS [256][256]; each wave runs the
// verified 16-row-packed scores MFMA (A=Y rows from LDS, B=X rows from
// global) and writes partials S4[y][b][h][6][6] (each entry exactly once:
// owner of (b,c) = block containing row b*6+c).
// ---------------------------------------------------------------------------
__global__ __launch_bounds__(512, 2) void gemmS(
    const bf16* __restrict__ A,      // Xb, 24576 x 1024
    const bf16* __restrict__ Mh,     // MhT, 5 x 1024 x 1024 (Bt layout)
    float* __restrict__ S4, int K) { // K = 1024
  const int h = blockIdx.z;
  const bf16* Bt = Mh + (size_t)h * 1048576;

  __shared__ __attribute__((aligned(16))) short ldsS[65536];  // 128 KiB

  const int tid = threadIdx.x;
  const int w = tid >> 6, l = tid & 63;
  const int l16 = l & 15, quad = l >> 4;
  const int wr = w >> 2, wc = w & 3;

  const size_t rm0 = (size_t)blockIdx.x * 256;
  const size_t cn0 = (size_t)blockIdx.y * 256;

  const int colS = ((l & 7) ^ (l >> 3)) * 8;
  const int rowS = w * 16 + (l >> 3);
  const short* pAs = (const short*)A + (rm0 + rowS) * (size_t)K + colS;
  const short* pBs = (const short*)Bt + (cn0 + rowS) * (size_t)K + colS;

  const int u0 = (quad ^ (l16 & 7)) * 8;
  const int u1 = ((quad + 4) ^ (l16 & 7)) * 8;

  f32x4 acc[8][4];
#pragma unroll
  for (int i = 0; i < 8; ++i)
#pragma unroll
    for (int j2i = 0; j2i < 4; ++j2i) acc[i][j2i] = (f32x4){0.f, 0.f, 0.f, 0.f};

  s16x8 af[4][2], bf0[2][2], bf1[2][2];

  const int T = K >> 6;  // 16

#ifdef HAVE_GLL
#define SA(BUF, H, KB) do {                                                          \
    __builtin_amdgcn_global_load_lds(AS1(pAs + (size_t)((H) * 128) * K + (KB)),      \
        AS3(ldsS + (BUF) * 32768 + (H) * 8192 + w * 1024), 16, 0, 0);                \
    __builtin_amdgcn_global_load_lds(AS1(pAs + (size_t)((H) * 128 + 8) * K + (KB)),  \
        AS3(ldsS + (BUF) * 32768 + (H) * 8192 + w * 1024 + 512), 16, 0, 0);          \
  } while (0)
#define SB(BUF, H, KB) do {                                                          \
    __builtin_amdgcn_global_load_lds(AS1(pBs + (size_t)((H) * 128) * K + (KB)),      \
        AS3(ldsS + (BUF) * 32768 + 16384 + (H) * 8192 + w * 1024), 16, 0, 0);        \
    __builtin_amdgcn_global_load_lds(AS1(pBs + (size_t)((H) * 128 + 8) * K + (KB)),  \
        AS3(ldsS + (BUF) * 32768 + 16384 + (H) * 8192 + w * 1024 + 512), 16, 0, 0);  \
  } while (0)
#else
#define SA(BUF, H, KB) do {                                                          \
    *(s16x8*)(ldsS + (BUF) * 32768 + (H) * 8192 + w * 1024 + l * 8) =                \
        *(const s16x8*)(pAs + (size_t)((H) * 128) * K + (KB));                       \
    *(s16x8*)(ldsS + (BUF) * 32768 + (H) * 8192 + w * 1024 + 512 + l * 8) =          \
        *(const s16x8*)(pAs + (size_t)((H) * 128 + 8) * K + (KB));                   \
  } while (0)
#define SB(BUF, H, KB) do {                                                          \
    *(s16x8*)(ldsS + (BUF) * 32768 + 16384 + (H) * 8192 + w * 1024 + l * 8) =        \
        *(const s16x8*)(pBs + (size_t)((H) * 128) * K + (KB));                       \
    *(s16x8*)(ldsS + (BUF) * 32768 + 16384 + (H) * 8192 + w * 1024 + 512 + l * 8) =  \
        *(const s16x8*)(pBs + (size_t)((H) * 128 + 8) * K + (KB));                   \
  } while (0)
#endif

#define LDA(BUF, MH) do {                                                            \
    _Pragma("unroll") for (int i = 0; i < 4; ++i) {                                  \
      const short* bse = ldsS + (BUF) * 32768 + wr * 8192 + (MH) * 4096 +            \
                         i * 1024 + l16 * 64;                                        \
      af[i][0] = *(const s16x8*)(bse + u0);                                          \
      af[i][1] = *(const s16x8*)(bse + u1);                                          \
    }                                                                                \
  } while (0)

#define LDB(BUF, NH, DST) do {                                                       \
    _Pragma("unroll") for (int n = 0; n < 2; ++n) {                                  \
      const short* bse = ldsS + (BUF) * 32768 + 16384 + (wc >> 1) * 8192 +           \
                         (wc & 1) * 4096 + (NH) * 2048 + n * 1024 + l16 * 64;        \
      DST[n][0] = *(const s16x8*)(bse + u0);                                         \
      DST[n][1] = *(const s16x8*)(bse + u1);                                         \
    }                                                                                \
  } while (0)

#define MFMAQ(MH, NH, BSET) do {                                                     \
    _Pragma("unroll") for (int i = 0; i < 4; ++i)                                    \
      _Pragma("unroll") for (int n = 0; n < 2; ++n) {                                \
        acc[(MH) * 4 + i][(NH) * 2 + n] = __builtin_amdgcn_mfma_f32_16x16x32_bf16(   \
            af[i][0], BSET[n][0], acc[(MH) * 4 + i][(NH) * 2 + n], 0, 0, 0);         \
        acc[(MH) * 4 + i][(NH) * 2 + n] = __builtin_amdgcn_mfma_f32_16x16x32_bf16(   \
            af[i][1], BSET[n][1], acc[(MH) * 4 + i][(NH) * 2 + n], 0, 0, 0);         \
      }                                                                              \
  } while (0)

#define BARX() asm volatile("s_barrier" ::: "memory")
#define LGKM0() do { asm volatile("s_waitcnt lgkmcnt(0)" ::: "memory");              \
                     __builtin_amdgcn_sched_barrier(0); } while (0)
#define VM6() do { asm volatile("s_waitcnt vmcnt(6)" ::: "memory");                  \
                   __builtin_amdgcn_sched_barrier(0); } while (0)
#define VM0() do { asm volatile("s_waitcnt vmcnt(0)" ::: "memory");                  \
                   __builtin_amdgcn_sched_barrier(0); } while (0)

#define TILE_STEP(BUF, t) do {                                                       \
    const int kN_ = ((t) + 1 < T ? (t) + 1 : T - 1) << 6;                            \
    const int k2_ = ((t) + 2 < T ? (t) + 2 : T - 1) << 6;                            \
    LDA(BUF, 0); LDB(BUF, 0, bf0); LDB(BUF, 1, bf1);                                 \
    SA((BUF) ^ 1, 1, kN_);                                                           \
    BARX(); LGKM0();                                                                 \
    __builtin_amdgcn_s_setprio(1); MFMAQ(0, 0, bf0); __builtin_amdgcn_s_setprio(0);  \
    BARX();                                                                          \
    SB(BUF, 0, k2_);                                                                 \
    BARX();                                                                          \
    __builtin_amdgcn_s_setprio(1); MFMAQ(0, 1, bf1); __builtin_amdgcn_s_setprio(0);  \
    BARX();                                                                          \
    LDA(BUF, 1);                                                                     \
    SB(BUF, 1, k2_);                                                                 \
    BARX(); LGKM0();                                                                 \
    __builtin_amdgcn_s_setprio(1); MFMAQ(1, 1, bf1); __builtin_amdgcn_s_setprio(0);  \
    BARX();                                                                          \
    SA(BUF, 0, k2_);                                                                 \
    VM6();                                                                           \
    BARX();                                                                          \
    __builtin_amdgcn_s_setprio(1); MFMAQ(1, 0, bf0); __builtin_amdgcn_s_setprio(0);  \
    BARX();                                                                          \
  } while (0)

  {
    const int k1_ = (T > 1 ? 1 : 0) << 6;
    SB(0, 0, 0); SB(0, 1, 0); SA(0, 0, 0); SA(0, 1, 0);
    SB(1, 0, k1_); SB(1, 1, k1_); SA(1, 0, k1_);
    VM6();
    BARX();
  }

  for (int t = 0; t < T; t += 2) {
    TILE_STEP(0, t);
    TILE_STEP(1, t + 1);
  }

  // ---- epilogue: drain glls, stage FULL Y tile to swizzled LDS ----
  VM0();
  BARX();
#pragma unroll
  for (int jj = 0; jj < 4; ++jj) {
    int C = wc * 64 + jj * 16 + l16;
#pragma unroll
    for (int i = 0; i < 8; ++i) {
#pragma unroll
      for (int r = 0; r < 4; ++r) {
        int Rl = wr * 128 + i * 16 + quad * 4 + r;
        int addr = Rl * 256 + (((C >> 3) ^ (Rl & 7)) << 3) + (C & 7);
        ldsS[addr] = f2s(acc[i][jj][r]);
      }
    }
  }
  __syncthreads();

  // ---- scores: per wave, pairs (b0,b1) packed {b0:rows 0-7, b1:8-15} ----
  const int R = (int)rm0;
  const int b_lo = R / 6, b_hi = (R + 255) / 6;
  int lr = l16 & 7; if (lr > 5) lr = 5;
  const size_t s4base = (size_t)blockIdx.y * 737280;

  for (int b0 = b_lo + 2 * w; b0 <= b_hi; b0 += 16) {
    const int b1 = b0 + 1;
    const int bb = (l16 < 8) ? b0 : b1;
    int grow = bb * 6 + lr; if (grow > 24575) grow = 24575;
    int yr = grow - R; yr = yr < 0 ? 0 : (yr > 255 ? 255 : yr);
    const short* xr = (const short*)A + (size_t)grow * K + cn0 + quad * 8;
    const int ybase = yr * 256, ysw = yr & 7;

    f32x4 sa = (f32x4){0.f, 0.f, 0.f, 0.f};
#pragma unroll
    for (int kk = 0; kk < 8; ++kk) {
      s16x8 ya = *(const s16x8*)(ldsS + ybase + (((kk * 4 + quad) ^ ysw) << 3));
      s16x8 xb = *(const s16x8*)(xr + kk * 32);
      sa = __builtin_amdgcn_mfma_f32_16x16x32_bf16(ya, xb, sa, 0, 0, 0);
    }

#pragma unroll
    for (int r = 0; r < 4; ++r) {
      int m = quad * 4 + r;
      if (l16 < 6) {
        if (m < 6) {
          int row = b0 * 6 + m;
          if (row >= R && row < R + 256)
            S4[s4base + ((size_t)b0 * 5 + h) * 36 + m * 6 + l16] = sa[r];
        }
      } else if (l16 >= 8 && l16 < 14) {
        if (m >= 8 && m < 14) {
          int c = m - 8, row = b1 * 6 + c;
          if (row >= R && row < R + 256)
            S4[s4base + ((size_t)b1 * 5 + h) * 36 + c * 6 + (l16 - 8)] = sa[r];
        }
      }
    }
  }
#undef SA
#undef SB
#undef LDA
#undef LDB
#undef MFMAQ
#undef BARX
#undef LGKM0
#undef VM6
#undef VM0
#undef TILE_STEP
}

// ---------------------------------------------------------------------------
// mid_ax: 4 batches per 256-thr block. p = sum of 4 S4 partials (+ v[d] via
// w2a1; exact 0 on these inputs), per-head softmax -> cat@linW+linb ->
// softmax -> A (to Afull), Xa = A @ x in place into Xb.
// ---------------------------------------------------------------------------
__global__ __launch_bounds__(256) void mid_ax(
    const float* __restrict__ S4, const float* __restrict__ w2a1,
    bf16* __restrict__ Xb,
    const float* __restrict__ linW, const float* __restrict__ linb,
    float* __restrict__ Afull) {
  const int tid = threadIdx.x, g = tid >> 6, t = tid & 63;
  const int b = blockIdx.x * 4 + g;
  __shared__ float p[4][5][6][6];
  __shared__ float vv[4][5][6];
  __shared__ float Ar[4][6][6];
  __shared__ float lw[30][6];
  __shared__ float lbv[6];

  if (tid < 30) {
#pragma unroll
    for (int j = 0; j < 6; ++j) lw[tid][j] = linW[tid * 6 + j];
  }
  if (tid < 6) lbv[tid] = linb[tid];

  if (t < 36) {
    size_t idx = ((size_t)b * 5) * 36 + t;
#pragma unroll
    for (int k = 0; k < 5; ++k)
      p[g][k][t / 6][t % 6] = S4[idx + k * 36] + S4[737280 + idx + k * 36] +
                              S4[2 * 737280 + idx + k * 36] +
                              S4[3 * 737280 + idx + k * 36];
  }
  if (t < 30) {  // v[d] for head k: dot(X row b*6+d, w2a1[k])
    int k = t / 6, d = t % 6;
    const s16x8* xr = (const s16x8*)((const short*)Xb + ((size_t)b * 6 + d) * 1024);
    const float* wv = w2a1 + k * 1024;
    float s = 0.f;
    for (int i = 0; i < 128; ++i) {
      s16x8 xv8 = xr[i];
#pragma unroll
      for (int e = 0; e < 8; ++e) s += s2f(xv8[e]) * wv[i * 8 + e];
    }
    vv[g][k][d] = s;
  }
  __syncthreads();

  if (t < 30) {  // per (k,c): softmax over d, in place
    int k = t / 6, c = t % 6;
    float v[6];
#pragma unroll
    for (int d = 0; d < 6; ++d) v[d] = p[g][k][c][d] + vv[g][k][d];
    float mx = v[0];
#pragma unroll
    for (int d = 1; d < 6; ++d) mx = fmaxf(mx, v[d]);
    float s = 0.f;
#pragma unroll
    for (int d = 0; d < 6; ++d) { v[d] = expf(v[d] - mx); s += v[d]; }
    float inv = 1.f / s;
#pragma unroll
    for (int d = 0; d < 6; ++d) p[g][k][c][d] = v[d] * inv;
  }
  __syncthreads();

  if (t < 6) {
    int c = t;
    float ap[6];
#pragma unroll
    for (int j = 0; j < 6; ++j) ap[j] = lbv[j];
    for (int k = 0; k < 5; ++k)
#pragma unroll
      for (int d = 0; d < 6; ++d) {
        float pv = p[g][k][c][d];
#pragma unroll
        for (int j = 0; j < 6; ++j) ap[j] += pv * lw[k * 6 + d][j];
      }
    float mx = ap[0];
#pragma unroll
    for (int j = 1; j < 6; ++j) mx = fmaxf(mx, ap[j]);
    float s = 0.f;
#pragma unroll
    for (int j = 0; j < 6; ++j) { ap[j] = expf(ap[j] - mx); s += ap[j]; }
    float inv = 1.f / s;
#pragma unroll
    for (int j = 0; j < 6; ++j) {
      float a = ap[j] * inv;
      Ar[g][c][j] = a;
      Afull[(size_t)b * 36 + c * 6 + j] = a;
    }
  }
  __syncthreads();

  // Xa = A @ x, in place into Xb (rows block-private, cols thread-private,
  // reads precede writes within thread: race-free).
  const int r6 = b * 6;
  short* xp = (short*)Xb;
#pragma unroll
  for (int it = 0; it < 2; ++it) {
    int c8 = (it * 64 + t) * 8;
    s16x8 xv[6];
#pragma unroll
    for (int d = 0; d < 6; ++d)
      xv[d] = *(const s16x8*)(xp + ((size_t)r6 + d) * 1024 + c8);
#pragma unroll
    for (int c = 0; c < 6; ++c) {
      s16x8 o;
#pragma unroll
      for (int e = 0; e < 8; ++e) {
        float s = 0.f;
#pragma unroll
        for (int d = 0; d < 6; ++d) s += Ar[g][c][d] * s2f(xv[d][e]);
        o[e] = f2s(s);
      }
      *(s16x8*)(xp + ((size_t)r6 + c) * 1024 + c8) = o;
    }
  }
}

// ---------------------------------------------------------------------------
// batch_out4: 4 batches per 256-thr block. out(f32) = BN2(A @ hw + gb2)
// ---------------------------------------------------------------------------
__global__ __launch_bounds__(256) void batch_out4(
    const float* __restrict__ Afull, const bf16* __restrict__ HW,
    const float* __restrict__ gb2,
    const float* __restrict__ g2, const float* __restrict__ b2,
    const float* __restrict__ m2, const float* __restrict__ v2,
    float* __restrict__ out) {
  const int tid = threadIdx.x, g = tid >> 6, t = tid & 63;
  const int b = blockIdx.x * 4 + g;
  __shared__ float Ar[4][36];
  __shared__ float sc[6], sm[6], sb[6];
  if (t < 36) Ar[g][t] = Afull[(size_t)b * 36 + t];
  if (tid < 6) {
    sc[tid] = g2[tid] * rsqrtf(v2[tid] + 1e-5f);
    sm[tid] = m2[tid];
    sb[tid] = b2[tid];
  }
  __syncthreads();
  for (int col = t; col < 256; col += 64) {
    float hw[6];
#pragma unroll
    for (int d = 0; d < 6; ++d) hw[d] = s2f(((const short*)HW)[((size_t)b * 6 + d) * 256 + col]);
    float gv = gb2[col];
#pragma unroll
    for (int c = 0; c < 6; ++c) {
      float o = gv;
#pragma unroll
      for (int d = 0; d < 6; ++d) o += Ar[g][c * 6 + d] * hw[d];
      o = (o - sm[c]) * sc[c] + sb[c];
      out[((size_t)b * 6 + c) * 256 + col] = o;
    }
  }
}

// ---------------------------------------------------------------------------
extern "C" void kernel_launch(void* const* d_in, const int* in_sizes, int n_in,
                              void* d_out, int out_size, void* d_ws, size_t ws_size,
                              hipStream_t stream) {
  const float* x    = (const float*)d_in[0];
  const float* aW1  = (const float*)d_in[1];
  const float* ab1  = (const float*)d_in[2];
  const float* aW2  = (const float*)d_in[3];
  const float* linW = (const float*)d_in[5];
  const float* linb = (const float*)d_in[6];
  const float* gW1  = (const float*)d_in[7];
  const float* gb1  = (const float*)d_in[8];
  const float* gW2  = (const float*)d_in[9];
  const float* gb2  = (const float*)d_in[10];
  const float* prelu = (const float*)d_in[11];
  const float* bn1g = (const float*)d_in[12];
  const float* bn1b = (const float*)d_in[13];
  const float* bn1m = (const float*)d_in[14];
  const float* bn1v = (const float*)d_in[15];
  const float* bn2g = (const float*)d_in[16];
  const float* bn2b = (const float*)d_in[17];
  const float* bn2m = (const float*)d_in[18];
  const float* bn2v = (const float*)d_in[19];

  char* ws = (char*)d_ws;
  bf16* W1b  = (bf16*)(ws + 0);          // 5 x 1024 x 512 (straight cvt)
  bf16* W2b  = (bf16*)(ws + 10485760);   // 5 x 1024 x 512
  bf16* G1T  = (bf16*)(ws + 20971520);   // 512 x 1024
  bf16* G2T  = (bf16*)(ws + 22020096);   // 256 x 512
  float* w2a1 = (float*)(ws + 22282240); // 5 x 1024
  float* Af  = (float*)(ws + 22302720);  // 4096 x 36
  float* S4  = (float*)(ws + 22892544);  // 4 x 4096 x 5 x 36
  bf16* Xb   = (bf16*)(ws + 34689024);   // 24576 x 1024 (x bf16, then Xa)
  bf16* MhT  = (bf16*)(ws + 85020672);   // 5 x 1024 x 1024
  bf16* PH   = (bf16*)(ws + 95506432);   // 24576 x 512 (H')
  bf16* PHW  = (bf16*)(ws + 120672256);  // 24576 x 256 (HW)
  // total 133,255,168 B << proven ws (>= 292 MB from R10-R12 runs)
  (void)ws_size;

  // 1. prep: cvts + transposes + w2a1
  prep_kernel<<<15508, 256, 0, stream>>>(x, Xb, aW1, W1b, aW2, W2b,
                                         gW1, G1T, gW2, G2T, ab1, w2a1);

  // 2. MhT_h = W2_h @ W1_h^T  (1024x1024, K=512), one dispatch, 5 z-slices
  {
    GJobs10 J{};
    for (int h = 0; h < 5; ++h)
      J.j[h] = GJob{W1b + (size_t)h * 524288, nullptr, 0,
                    MhT + (size_t)h * 1048576, W2b + (size_t)h * 524288};
    gemm256_8ph<<<dim3(4, 4, 5), 512, 0, stream>>>(
        W2b, J, -1, nullptr, nullptr, nullptr, nullptr, nullptr, 1024, 1024, 512);
  }

  // 3. gemmS: Y = X @ M_h with fused scores -> S4 (no Y to HBM)
  gemmS<<<dim3(96, 4, 5), 512, 0, stream>>>(Xb, MhT, S4, 1024);

  // 4. mid: S4 sum + v -> softmaxes -> A -> Xa in place
  mid_ax<<<1024, 256, 0, stream>>>(S4, w2a1, Xb, linW, linb, Af);

  // 5. H' = Xa @ gW1 with fused gb1 + PReLU + BN1 -> PH
  {
    GJobs10 JH{};
    JH.j[0] = GJob{G1T, gb1, 0, PH, nullptr};
    gemm256_8ph<<<dim3(96, 2, 1), 512, 0, stream>>>(
        Xb, JH, 0, prelu, bn1g, bn1b, bn1m, bn1v, 24576, 512, 1024);
  }

  // 6. HW = H' @ gW2 -> PHW
  gemm_bt<0><<<dim3(192, 2, 1), 256, 0, stream>>>(
      PH, G2T, G2T, nullptr, nullptr, 0, PHW, PHW, 24576, 256, 512);

  // 7. out = BN2(A @ HW + gb2)
  batch_out4<<<1024, 256, 0, stream>>>(Af, PHW, gb2, bn2g, bn2b, bn2m, bn2v,
                                       (float*)d_out);
}